// Round 3
// baseline (379.452 us; speedup 1.0000x reference)
//
#include <hip/hip_runtime.h>
#include <hip/hip_bf16.h>

// Shapes (fixed by the reference)
#define QN 64
#define SQ 32
#define CN 256
#define SC 256
#define HD 768
#define DD 128

typedef __attribute__((ext_vector_type(8))) short short8;   // 8 bf16 = 4 VGPR
typedef __attribute__((ext_vector_type(4))) float f32x4;    // MFMA acc

// ---- bf16 pack helpers (RNE) ----
static __device__ __forceinline__ unsigned short f2bf(float x) {
  unsigned u = __float_as_uint(x);
  unsigned r = 0x7FFFu + ((u >> 16) & 1u);
  return (unsigned short)((u + r) >> 16);
}
static __device__ __forceinline__ unsigned pack2(float a, float b) {
  return (unsigned)f2bf(a) | ((unsigned)f2bf(b) << 16);
}

// ---- async global->LDS, 16B/lane; LDS dest = wave-uniform base + lane*16 ----
typedef const __attribute__((address_space(1))) unsigned int* as1_u32p;
typedef __attribute__((address_space(3))) unsigned int* as3_u32p;
static __device__ __forceinline__ void gl_lds16(const void* g, void* l) {
  __builtin_amdgcn_global_load_lds((as1_u32p)g, (as3_u32p)l, 16, 0, 0);
}

// ---------------------------------------------------------------------------
// Prep (fused):
//  blocks [0,128):  WtS[d][kc'] = bf16(W[k][d]) in 16B chunks (8 bf16), XOR
//                   swizzled within 8-chunk groups: kc' = (kc&~7)|((kc&7)^(d&7)).
//  blocks [128,448): pooled l2norm rows (64 q + 256 c); q rows also zero
//                   qcolP pad row 31.
// ---------------------------------------------------------------------------
__global__ __launch_bounds__(256) void prep_kernel(
    const float* __restrict__ W,
    const float* __restrict__ qh, const int* __restrict__ qm,
    const float* __restrict__ ch, const int* __restrict__ cm,
    unsigned short* __restrict__ WtS,
    float* __restrict__ outq, float* __restrict__ outc,
    unsigned short* __restrict__ qcolP) {
  __shared__ float red[4];
  int bid = blockIdx.x, tid = threadIdx.x;

  if (bid < DD) {  // W transpose-convert, swizzled chunks
    int d = bid;
    if (tid < 96) {
      int kc = tid;
      unsigned p[4];
#pragma unroll
      for (int e = 0; e < 4; ++e) {
        float a = W[(size_t)(kc * 8 + 2 * e) * DD + d];
        float b = W[(size_t)(kc * 8 + 2 * e + 1) * DD + d];
        p[e] = pack2(a, b);
      }
      int kcp = (kc & ~7) | ((kc & 7) ^ (d & 7));
      *(uint4*)&WtS[((size_t)d * 96 + kcp) * 8] = *(uint4*)p;
    }
    return;
  }

  int row = bid - DD;
  const float* src;
  float* dst;
  float m;
  if (row < QN) {
    src = qh + (size_t)row * SQ * HD;
    m = (float)qm[row * SQ];
    dst = outq + (size_t)row * HD;
  } else {
    int b = row - QN;
    src = ch + (size_t)b * SC * HD;
    m = (float)cm[b * SC];
    dst = outc + (size_t)b * HD;
  }
  float ss = 0.f;
  for (int k = tid; k < HD; k += 256) {
    float v = src[k] * m;
    ss += v * v;
  }
  int lane = tid & 63, wv = tid >> 6;
  for (int off = 32; off; off >>= 1) ss += __shfl_xor(ss, off);
  if (lane == 0) red[wv] = ss;
  __syncthreads();
  float tot = red[0] + red[1] + red[2] + red[3];
  float inv = 1.f / fmaxf(sqrtf(tot), 1e-12f);
  for (int k = tid; k < HD; k += 256) dst[k] = src[k] * m * inv;
  if (row < QN && tid < 64)
    ((unsigned*)(qcolP + ((size_t)row * 32 + 31) * DD))[tid] = 0u;
}

// ---------------------------------------------------------------------------
// Projection GEMM (MFMA): col = l2norm(m*(h@W) + b)
//  v3: CONTIGUOUS A STREAMING. 32 rows/block -> each block reads one 96 KB
//  contiguous chunk of h (fixes the 256B-burst/3KB-stride DRAM pattern that
//  capped r0-r2 at ~1.8 TB/s). A converted to bf16 once, stored XOR-swizzled
//  in a 48 KB LDS tile holding ALL of K; the 12-step k-loop then touches
//  global only for the tiny L2-hot W tiles (16 KB, double-buffered).
//  Waves split 2x2 (row-half x d-half) -> per-wave W LDS reads halved.
//  LDS 48+32 = 80 KB -> 2 blocks/CU; block X k-loop overlaps block Y stream.
//  Blocks [0,2040): c tokens (exact). [2040,2102): q tokens (exact).
//  Mask applied in epilogue (exact: (h*m)@W + b == m*(h@W) + b).
// ---------------------------------------------------------------------------
union ProjWLDS {
  unsigned short w[2][128 * 64];  // 2 x 16 KB W double-buffer
  float cep[32 * 132];            // 16.9 KB epilogue staging
};

__global__ __launch_bounds__(256, 2) void proj_kernel(
    const float* __restrict__ q_hidden, const float* __restrict__ c_hidden,
    const int* __restrict__ q_mask, const int* __restrict__ c_mask,
    const unsigned short* __restrict__ WtS, const float* __restrict__ bias,
    unsigned short* __restrict__ qcol, unsigned short* __restrict__ ccol) {
  __shared__ unsigned short Alds[32 * 768];  // 48 KB, chunk-XOR-swizzled bf16
  __shared__ ProjWLDS u;
  int bx = blockIdx.x;
  int isQ = (bx >= 2040) ? 1 : 0;
  int base = isQ ? (bx - 2040) : bx;
  int tid = threadIdx.x, lane = tid & 63, wv = tid >> 6;
  int lm = lane & 15, lq = lane >> 4;
  int wi = wv & 1;        // row-half: rows 16*wi .. 16*wi+15
  int wj = wv >> 1;       // d-half:   d 64*wj .. 64*wj+63

  // ---- A staging plan: 12 bf16 16B-chunks per thread (3072 total = 32x96) ----
  const float* asrc[12];
  unsigned aoff[12];
#pragma unroll
  for (int i = 0; i < 12; ++i) {
    unsigned j = i * 256 + tid;
    unsigned row = j / 96, c = j - row * 96;
    unsigned g = base * 32 + row;
    const float* hp;
    if (isQ) {  // 62 blocks * 32 = 1984 = 64*31 exact
      unsigned qq = g / 31, t = g - qq * 31;
      hp = q_hidden + ((size_t)qq * SQ + t + 1) * HD;
    } else {    // 2040 blocks * 32 = 65280 = 256*255 exact
      unsigned cb = g / 255, t = g - cb * 255;
      hp = c_hidden + ((size_t)cb * SC + t + 1) * HD;
    }
    asrc[i] = hp + c * 8;
    unsigned cp = (c & ~7u) | ((c & 7u) ^ (row & 7u));
    aoff[i] = row * 768 + cp * 8;
  }

  // ---- W staging sources: 4 slots/thread (linear copy of pre-swizzled WtS) ----
  const unsigned short* wptr[4];
#pragma unroll
  for (int i = 0; i < 4; ++i) {
    int d = i * 32 + (tid >> 3);
    wptr[i] = WtS + ((size_t)d * 96 + (tid & 7)) * 8;
  }

  // ---- issue the contiguous A stream (24 float4 loads), then W(0) DMA ----
  float4 av[12][2];
#pragma unroll
  for (int i = 0; i < 12; ++i) {
    av[i][0] = *(const float4*)(asrc[i]);
    av[i][1] = *(const float4*)(asrc[i] + 4);
  }
#pragma unroll
  for (int i = 0; i < 4; ++i)
    gl_lds16(wptr[i], (char*)&u.w[0][0] + (size_t)(i * 256 + wv * 64) * 16);

  // ---- convert + swizzled ds_write (compiler interleaves via counted vmcnt) ----
#pragma unroll
  for (int i = 0; i < 12; ++i) {
    unsigned pk[4];
    pk[0] = pack2(av[i][0].x, av[i][0].y);
    pk[1] = pack2(av[i][0].z, av[i][0].w);
    pk[2] = pack2(av[i][1].x, av[i][1].y);
    pk[3] = pack2(av[i][1].z, av[i][1].w);
    *(uint4*)&Alds[aoff[i]] = *(uint4*)pk;
  }

  f32x4 acc[4];
#pragma unroll
  for (int n = 0; n < 4; ++n) acc[n] = (f32x4){0.f, 0.f, 0.f, 0.f};

  __syncthreads();  // A tile + W(0) ready

  int arow = 16 * wi + lm;  // this lane's A row
  for (int t = 0; t < 12; ++t) {
    int cb_ = t & 1;
    if (t < 11) {  // prefetch W(t+1) into the other buffer (L2-hot, cheap)
#pragma unroll
      for (int i = 0; i < 4; ++i)
        gl_lds16(wptr[i] + (t + 1) * 64,
                 (char*)&u.w[cb_ ^ 1][0] + (size_t)(i * 256 + wv * 64) * 16);
    }
#pragma unroll
    for (int w = 0; w < 2; ++w) {
      int coct = t * 8 + ((w * 4 + lq) ^ (lm & 7));
      short8 afr = *(const short8*)&Alds[arow * 768 + coct * 8];
#pragma unroll
      for (int n = 0; n < 4; ++n) {
        int d = (wj * 4 + n) * 16 + lm;
        int pc = (w * 4 + lq) ^ (lm & 7);
        short8 bfr = *(const short8*)&u.w[cb_][d * 64 + pc * 8];
        acc[n] = __builtin_amdgcn_mfma_f32_16x16x32_bf16(afr, bfr, acc[n], 0, 0, 0);
      }
    }
    __syncthreads();
  }

  // ---- epilogue: 32 rows through cep (reuses W LDS; all W reads done) ----
#pragma unroll
  for (int n = 0; n < 4; ++n)
#pragma unroll
    for (int r = 0; r < 4; ++r)
      u.cep[(16 * wi + lq * 4 + r) * 132 + wj * 64 + n * 16 + lm] = acc[n][r];
  __syncthreads();

  int tk = tid >> 3, qt = tid & 7;  // row 0..31, 16-d slice 0..7
  int g = base * 32 + tk;
  int qq, t;
  float fm;
  if (isQ) {
    qq = g / 31; t = g - qq * 31;
    fm = (float)q_mask[qq * SQ + t + 1];
  } else {
    qq = g / 255; t = g - qq * 255;
    fm = (float)c_mask[qq * SC + t + 1];
  }

  float v[16];
  float ss = 0.f;
#pragma unroll
  for (int j = 0; j < 4; ++j) {
    float4 cv = *(const float4*)&u.cep[tk * 132 + qt * 16 + j * 4];
    float4 bv = *(const float4*)&bias[qt * 16 + j * 4];
    v[4 * j + 0] = cv.x * fm + bv.x; v[4 * j + 1] = cv.y * fm + bv.y;
    v[4 * j + 2] = cv.z * fm + bv.z; v[4 * j + 3] = cv.w * fm + bv.w;
#pragma unroll
    for (int e = 0; e < 4; ++e) ss += v[4 * j + e] * v[4 * j + e];
  }
  ss += __shfl_xor(ss, 1);
  ss += __shfl_xor(ss, 2);
  ss += __shfl_xor(ss, 4);
  float inv = 1.f / fmaxf(sqrtf(ss), 1e-12f);

  uint4 pk4[2];
#pragma unroll
  for (int j = 0; j < 2; ++j) {
    unsigned p[4];
#pragma unroll
    for (int e = 0; e < 4; ++e)
      p[e] = pack2(v[8 * j + 2 * e] * inv, v[8 * j + 2 * e + 1] * inv);
    pk4[j] = *(uint4*)p;
  }

  if (isQ) {
    uint4* dst = (uint4*)(qcol + ((size_t)qq * 32 + t) * DD);
#pragma unroll
    for (int j = 0; j < 2; ++j) dst[qt * 2 + j] = pk4[j];
  } else {
    uint4* rowp = (uint4*)(ccol + ((size_t)qq * 256 + t) * DD);
#pragma unroll
    for (int j = 0; j < 2; ++j) {
      int kc = qt * 2 + j;
      int p = (kc & 8) | ((kc & 7) ^ (t & 7));
      rowp[p] = pk4[j];
    }
    if (t == 254) {  // duplicate into pad row 255 (row&7 = 7); next row = +16 uint4
      uint4* rowp2 = rowp + 16;
#pragma unroll
      for (int j = 0; j < 2; ++j) {
        int kc = qt * 2 + j;
        int p = (kc & 8) | ((kc & 7) ^ 7);
        rowp2[p] = pk4[j];
      }
    }
  }
}

// ---------------------------------------------------------------------------
// Sim (MFMA): sim[q,c] = (sum_i max_j qcol[q,i]·ccol[c,j]) / denom[q]
// Grid (128, 4), 256 thr = 4 waves, 2 blocks/CU. 4 q per wave (16 q/block),
// 2 c-docs per block processed as 4 half-tiles (128 c-rows = 32 KB each),
// double-buffered: stage(half+1) issued before compute(half) — one barrier
// per half. ccol is pre-swizzled by proj; frag reads use the same XOR.
// ---------------------------------------------------------------------------
__global__ __launch_bounds__(256, 2) void sim_kernel(
    const unsigned short* __restrict__ qcolP,  // [64][32][128], row 31 zero
    const unsigned short* __restrict__ ccol,   // swizzled, row 255 dup
    const int* __restrict__ qmask,
    float* __restrict__ sim) {
  __shared__ unsigned short cbuf[2][128 * 128];  // 2 x 32 KB
  int tid = threadIdx.x, lane = tid & 63, wv = tid >> 6;
  int lm = lane & 15, lq = lane >> 4;
  int qb = blockIdx.y * 16 + wv * 4;  // 4 q per wave
  int c0 = blockIdx.x * 2;

  // B fragments (q side): af[q2][it][kf]
  short8 af[4][2][4];
#pragma unroll
  for (int q2 = 0; q2 < 4; ++q2)
#pragma unroll
    for (int it = 0; it < 2; ++it)
#pragma unroll
      for (int kf = 0; kf < 4; ++kf)
        af[q2][it][kf] = *(const short8*)(qcolP +
            (((size_t)(qb + q2) * 32 + it * 16 + lm) * DD + kf * 32 + lq * 8));

  float dinv[4];
#pragma unroll
  for (int q2 = 0; q2 < 4; ++q2) {
    float v = (lane >= 1 && lane < 32) ? (float)qmask[(qb + q2) * SQ + lane] : 0.f;
    for (int off = 1; off < 64; off <<= 1) v += __shfl_xor(v, off);
    dinv[q2] = 1.f / v;
  }

  const unsigned short* csrc = ccol + (size_t)c0 * SC * DD;  // 4 contiguous halves

  // prologue: stage half 0 into buffer 0
#pragma unroll
  for (int i = 0; i < 8; ++i)
    gl_lds16(csrc + (size_t)(i * 256 + tid) * 8,
             (char*)&cbuf[0][0] + (size_t)(i * 256 + wv * 64) * 16);
  __syncthreads();

  float rmax[4][2];
  for (int ht = 0; ht < 4; ++ht) {  // 2 c-docs x 2 halves
    int b = ht & 1;
    if (!(ht & 1)) {
#pragma unroll
      for (int q2 = 0; q2 < 4; ++q2) {
        rmax[q2][0] = -__builtin_inff();
        rmax[q2][1] = -__builtin_inff();
      }
    }
    if (ht < 3) {  // prefetch next half into other buffer (2-phase)
      const unsigned short* s2 = csrc + (size_t)(ht + 1) * 16384;
#pragma unroll
      for (int i = 0; i < 8; ++i)
        gl_lds16(s2 + (size_t)(i * 256 + tid) * 8,
                 (char*)&cbuf[b ^ 1][0] + (size_t)(i * 256 + wv * 64) * 16);
    }

    for (int jt = 0; jt < 8; ++jt) {
      short8 cf[4];  // A operand: c rows jt*16+lm of this half
#pragma unroll
      for (int kf = 0; kf < 4; ++kf) {
        int row = jt * 16 + lm;
        int kc = kf * 4 + lq;
        int p = (kc & 8) | ((kc & 7) ^ (row & 7));
        cf[kf] = *(const short8*)&cbuf[b][(size_t)(row * 16 + p) * 8];
      }
#pragma unroll
      for (int q2 = 0; q2 < 4; ++q2)
#pragma unroll
        for (int it = 0; it < 2; ++it) {
          f32x4 acc = (f32x4){0.f, 0.f, 0.f, 0.f};
#pragma unroll
          for (int kf = 0; kf < 4; ++kf)
            acc = __builtin_amdgcn_mfma_f32_16x16x32_bf16(cf[kf], af[q2][it][kf], acc, 0, 0, 0);
          float loc = fmaxf(fmaxf(acc[0], acc[1]), fmaxf(acc[2], acc[3]));
          rmax[q2][it] = fmaxf(rmax[q2][it], loc);
        }
    }

    if (ht & 1) {  // finalize doc c = c0 + (ht>>1)
      int c = c0 + (ht >> 1);
#pragma unroll
      for (int q2 = 0; q2 < 4; ++q2) {
        float m0 = rmax[q2][0], m1 = rmax[q2][1];
        m0 = fmaxf(m0, __shfl_xor(m0, 16)); m0 = fmaxf(m0, __shfl_xor(m0, 32));
        m1 = fmaxf(m1, __shfl_xor(m1, 16)); m1 = fmaxf(m1, __shfl_xor(m1, 32));
        // q-row i = lm (+16 for it=1); pad row 31 = (it=1, lm=15) excluded
        float s = m0 + ((lm == 15) ? 0.f : m1);
        s += __shfl_xor(s, 1); s += __shfl_xor(s, 2);
        s += __shfl_xor(s, 4); s += __shfl_xor(s, 8);
        if (lane == 0) sim[(qb + q2) * CN + c] = s * dinv[q2];
      }
    }
    __syncthreads();  // buf[b] consumed by all waves; safe to restage next iter
  }
}

// ---------------------------------------------------------------------------
extern "C" void kernel_launch(void* const* d_in, const int* in_sizes, int n_in,
                              void* d_out, int out_size, void* d_ws, size_t ws_size,
                              hipStream_t stream) {
  const float* q_hidden = (const float*)d_in[0];
  const float* c_hidden = (const float*)d_in[1];
  const float* W = (const float*)d_in[2];
  const float* bias = (const float*)d_in[3];
  const int* q_mask = (const int*)d_in[4];
  const int* c_mask = (const int*)d_in[5];

  float* out = (float*)d_out;
  float* sim = out;                      // 64*256
  float* q_pooled = out + QN * CN;       // 64*768
  float* c_pooled = q_pooled + QN * HD;  // 256*768

  unsigned short* WtS   = (unsigned short*)d_ws;                        // 192 KB
  unsigned short* qcolP = (unsigned short*)((char*)d_ws + (256 << 10)); // 512 KB
  unsigned short* ccol  = (unsigned short*)((char*)d_ws + (1 << 20));   // 16 MB

  prep_kernel<<<DD + QN + CN, 256, 0, stream>>>(W, q_hidden, q_mask, c_hidden, c_mask,
                                                WtS, q_pooled, c_pooled, qcolP);
  proj_kernel<<<2102, 256, 0, stream>>>(q_hidden, c_hidden, q_mask, c_mask,
                                        WtS, bias, qcolP, ccol);
  sim_kernel<<<dim3(128, 4), 256, 0, stream>>>(qcolP, ccol, q_mask, sim);
}

// Round 4
// 348.692 us; speedup vs baseline: 1.0882x; 1.0882x over previous
//
#include <hip/hip_runtime.h>
#include <hip/hip_bf16.h>

// Shapes (fixed by the reference)
#define QN 64
#define SQ 32
#define CN 256
#define SC 256
#define HD 768
#define DD 128

typedef __attribute__((ext_vector_type(8))) short short8;   // 8 bf16 = 4 VGPR
typedef __attribute__((ext_vector_type(4))) float f32x4;    // MFMA acc

// ---- bf16 pack helpers (RNE) ----
static __device__ __forceinline__ unsigned short f2bf(float x) {
  unsigned u = __float_as_uint(x);
  unsigned r = 0x7FFFu + ((u >> 16) & 1u);
  return (unsigned short)((u + r) >> 16);
}
static __device__ __forceinline__ unsigned pack2(float a, float b) {
  return (unsigned)f2bf(a) | ((unsigned)f2bf(b) << 16);
}

// ---- async global->LDS, 16B/lane; LDS dest = wave-uniform base + lane*16 ----
typedef const __attribute__((address_space(1))) unsigned int* as1_u32p;
typedef __attribute__((address_space(3))) unsigned int* as3_u32p;
static __device__ __forceinline__ void gl_lds16(const void* g, void* l) {
  __builtin_amdgcn_global_load_lds((as1_u32p)g, (as3_u32p)l, 16, 0, 0);
}

// ---------------------------------------------------------------------------
// Prep (fused):
//  blocks [0,128):  WtS[d][kc'] = bf16(W[k][d]) in 16B chunks (8 bf16), XOR
//                   swizzled within 8-chunk groups: kc' = (kc&~7)|((kc&7)^(d&7)).
//  blocks [128,448): pooled l2norm rows (64 q + 256 c); q rows also zero
//                   qcolP pad row 31.
// ---------------------------------------------------------------------------
__global__ __launch_bounds__(256) void prep_kernel(
    const float* __restrict__ W,
    const float* __restrict__ qh, const int* __restrict__ qm,
    const float* __restrict__ ch, const int* __restrict__ cm,
    unsigned short* __restrict__ WtS,
    float* __restrict__ outq, float* __restrict__ outc,
    unsigned short* __restrict__ qcolP) {
  __shared__ float red[4];
  int bid = blockIdx.x, tid = threadIdx.x;

  if (bid < DD) {  // W transpose-convert, swizzled chunks
    int d = bid;
    if (tid < 96) {
      int kc = tid;
      unsigned p[4];
#pragma unroll
      for (int e = 0; e < 4; ++e) {
        float a = W[(size_t)(kc * 8 + 2 * e) * DD + d];
        float b = W[(size_t)(kc * 8 + 2 * e + 1) * DD + d];
        p[e] = pack2(a, b);
      }
      int kcp = (kc & ~7) | ((kc & 7) ^ (d & 7));
      *(uint4*)&WtS[((size_t)d * 96 + kcp) * 8] = *(uint4*)p;
    }
    return;
  }

  int row = bid - DD;
  const float* src;
  float* dst;
  float m;
  if (row < QN) {
    src = qh + (size_t)row * SQ * HD;
    m = (float)qm[row * SQ];
    dst = outq + (size_t)row * HD;
  } else {
    int b = row - QN;
    src = ch + (size_t)b * SC * HD;
    m = (float)cm[b * SC];
    dst = outc + (size_t)b * HD;
  }
  float ss = 0.f;
  for (int k = tid; k < HD; k += 256) {
    float v = src[k] * m;
    ss += v * v;
  }
  int lane = tid & 63, wv = tid >> 6;
  for (int off = 32; off; off >>= 1) ss += __shfl_xor(ss, off);
  if (lane == 0) red[wv] = ss;
  __syncthreads();
  float tot = red[0] + red[1] + red[2] + red[3];
  float inv = 1.f / fmaxf(sqrtf(tot), 1e-12f);
  for (int k = tid; k < HD; k += 256) dst[k] = src[k] * m * inv;
  if (row < QN && tid < 64)
    ((unsigned*)(qcolP + ((size_t)row * 32 + 31) * DD))[tid] = 0u;
}

// ---------------------------------------------------------------------------
// Projection GEMM (MFMA): col = l2norm(m*(h@W) + b)
//  v4 = r2 structure (A global->register, W in LDS dbuf) + MASK-SKIP:
//  mask = randint(0,2) -> ~50% of tokens have m=0, and for those
//  col = l2norm(b) needs NO h data. Per-lane row predicate pm[] skips the
//  A loads for masked rows (exec-masked loads fetch only active lanes'
//  lines -> A traffic ~halves). A regs are zero-initialized so masked rows
//  contribute exact 0 to acc; epilogue's *fm keeps it exact either way.
//  M=128/block (2 row-tiles per wave), BK=64, 12 k-steps, A prefetched one
//  step ahead into named reg sets (Pa/Pb). Blocks [0,510): c. [510,526): q.
// ---------------------------------------------------------------------------
union ProjLDS {
  unsigned short w[2][128 * 64];  // 2 x 16 KB W double-buffer
  float cep[64 * 132];            // 33.8 KB epilogue staging (per 64-row half)
};

__global__ __launch_bounds__(256, 2) void proj_kernel(
    const float* __restrict__ q_hidden, const float* __restrict__ c_hidden,
    const int* __restrict__ q_mask, const int* __restrict__ c_mask,
    const unsigned short* __restrict__ WtS, const float* __restrict__ bias,
    unsigned short* __restrict__ qcol, unsigned short* __restrict__ ccol) {
  __shared__ ProjLDS u;
  int bx = blockIdx.x;
  int isQ = (bx >= 510) ? 1 : 0;
  int base = isQ ? (bx - 510) : bx;
  int tid = threadIdx.x, lane = tid & 63, wv = tid >> 6;
  int lm = lane & 15, lq = lane >> 4;

  // ---- A row base pointers + per-row mask predicate, one per 16-row tile ----
  const float* abase[2];
  int pm[2];
#pragma unroll
  for (int mt = 0; mt < 2; ++mt) {
    int g = base * 128 + wv * 32 + mt * 16 + lm;
    const float* hp;
    if (isQ) {  // rows up to 2047 -> clamp (dup row 1983, benign)
      g = (g > 1983) ? 1983 : g;
      int qq = g / 31, t = g - qq * 31;
      hp = q_hidden + ((size_t)qq * SQ + t + 1) * HD;
      pm[mt] = q_mask[qq * SQ + t + 1];
    } else {    // 510 blocks * 128 = 65280 rows exactly
      int cb = g / 255, t = g - cb * 255;
      hp = c_hidden + ((size_t)cb * SC + t + 1) * HD;
      pm[mt] = c_mask[cb * SC + t + 1];
    }
    abase[mt] = hp + lq * 8;  // lane's k-slice origin
  }

  // ---- W staging sources: 4 slots/thread (linear copy of pre-swizzled WtS) ----
  const unsigned short* wptr[4];
#pragma unroll
  for (int i = 0; i < 4; ++i) {
    int d = i * 32 + (tid >> 3);
    wptr[i] = WtS + ((size_t)d * 96 + (tid & 7)) * 8;
  }

  f32x4 acc[2][8];
#pragma unroll
  for (int i = 0; i < 2; ++i)
#pragma unroll
    for (int j = 0; j < 8; ++j) acc[i][j] = (f32x4){0.f, 0.f, 0.f, 0.f};

  // A prefetch double-set; zero-init so masked (never-loaded) rows are exact 0.
  float4 Pa[8], Pb[8];
#pragma unroll
  for (int i = 0; i < 8; ++i) {
    Pa[i] = (float4){0.f, 0.f, 0.f, 0.f};
    Pb[i] = (float4){0.f, 0.f, 0.f, 0.f};
  }

  // ---- prologue: A(0)->Pa (masked lanes skip), W(0)->buf0 (DMA) ----
#pragma unroll
  for (int mt = 0; mt < 2; ++mt)
    if (pm[mt]) {
#pragma unroll
      for (int w = 0; w < 2; ++w) {
        Pa[w * 4 + mt * 2 + 0] = *(const float4*)(abase[mt] + w * 32);
        Pa[w * 4 + mt * 2 + 1] = *(const float4*)(abase[mt] + w * 32 + 4);
      }
    }
#pragma unroll
  for (int i = 0; i < 4; ++i)
    gl_lds16(wptr[i], (char*)&u.w[0][0] + (size_t)(i * 256 + wv * 64) * 16);
  __syncthreads();

  // One pipeline step: compute step t from (PC, buf CB); prefetch t+1 into
  // (PN, buf NB) first so loads overlap the compute below. Masked lanes
  // never overwrite PN -> stays 0 -> exact 0 contribution.
#define PROJ_STEP(t, PC, PN, CB, NB, PREFETCH)                                 \
  {                                                                            \
    if (PREFETCH) {                                                            \
      _Pragma("unroll")                                                        \
      for (int mt = 0; mt < 2; ++mt)                                           \
        if (pm[mt]) {                                                          \
          _Pragma("unroll")                                                    \
          for (int w = 0; w < 2; ++w) {                                        \
            PN[w * 4 + mt * 2 + 0] =                                           \
                *(const float4*)(abase[mt] + (t + 1) * 64 + w * 32);           \
            PN[w * 4 + mt * 2 + 1] =                                           \
                *(const float4*)(abase[mt] + (t + 1) * 64 + w * 32 + 4);       \
          }                                                                    \
        }                                                                      \
      _Pragma("unroll")                                                        \
      for (int i = 0; i < 4; ++i)                                              \
        gl_lds16(wptr[i] + (t + 1) * 64,                                       \
                 (char*)&u.w[NB][0] + (size_t)(i * 256 + wv * 64) * 16);       \
    }                                                                          \
    _Pragma("unroll")                                                          \
    for (int w = 0; w < 2; ++w) {                                              \
      short8 afr[2];                                                           \
      _Pragma("unroll")                                                        \
      for (int mt = 0; mt < 2; ++mt) {                                         \
        float4 a0 = PC[w * 4 + mt * 2], a1 = PC[w * 4 + mt * 2 + 1];           \
        unsigned pk[4];                                                        \
        pk[0] = pack2(a0.x, a0.y); pk[1] = pack2(a0.z, a0.w);                  \
        pk[2] = pack2(a1.x, a1.y); pk[3] = pack2(a1.z, a1.w);                  \
        afr[mt] = *(short8*)pk;                                                \
      }                                                                        \
      _Pragma("unroll")                                                        \
      for (int nt = 0; nt < 8; ++nt) {                                         \
        int d = nt * 16 + lm;                                                  \
        int pc = (w * 4 + lq) ^ (lm & 7);                                      \
        short8 bfr = *(const short8*)&u.w[CB][d * 64 + pc * 8];                \
        acc[0][nt] = __builtin_amdgcn_mfma_f32_16x16x32_bf16(afr[0], bfr,      \
                                                             acc[0][nt], 0, 0, 0); \
        acc[1][nt] = __builtin_amdgcn_mfma_f32_16x16x32_bf16(afr[1], bfr,      \
                                                             acc[1][nt], 0, 0, 0); \
      }                                                                        \
    }                                                                          \
    __syncthreads();                                                           \
  }

#pragma unroll
  for (int s = 0; s < 12; s += 2) {
    PROJ_STEP(s, Pa, Pb, 0, 1, 1);
    PROJ_STEP(s + 1, Pb, Pa, 1, 0, (s + 1 < 11));
  }
#undef PROJ_STEP

  // ---- epilogue: two 64-row halves through LDS (reuses staging space) ----
  int tk = tid >> 2, qt = tid & 3;  // row-in-half, 32-d quarter
#pragma unroll
  for (int h = 0; h < 2; ++h) {
    __syncthreads();
    if ((wv >> 1) == h) {
#pragma unroll
      for (int mt = 0; mt < 2; ++mt)
#pragma unroll
        for (int nt = 0; nt < 8; ++nt)
#pragma unroll
          for (int r = 0; r < 4; ++r) {
            int row = (wv & 1) * 32 + mt * 16 + lq * 4 + r;
            u.cep[row * 132 + nt * 16 + lm] = acc[mt][nt][r];
          }
    }
    __syncthreads();

    int g = base * 128 + h * 64 + tk;
    int qq, t, valid = 1;
    float fm;
    if (isQ) {
      if (g > 1983) { valid = 0; g = 1983; }
      qq = g / 31; t = g - qq * 31;
      fm = (float)q_mask[qq * SQ + t + 1];
    } else {
      qq = g / 255; t = g - qq * 255;
      fm = (float)c_mask[qq * SC + t + 1];
    }

    float v[32];
    float ss = 0.f;
#pragma unroll
    for (int j = 0; j < 8; ++j) {
      float4 cv = *(const float4*)&u.cep[tk * 132 + qt * 32 + j * 4];
      float4 bv = *(const float4*)&bias[qt * 32 + j * 4];
      v[4 * j + 0] = cv.x * fm + bv.x; v[4 * j + 1] = cv.y * fm + bv.y;
      v[4 * j + 2] = cv.z * fm + bv.z; v[4 * j + 3] = cv.w * fm + bv.w;
#pragma unroll
      for (int e = 0; e < 4; ++e) ss += v[4 * j + e] * v[4 * j + e];
    }
    ss += __shfl_xor(ss, 1);
    ss += __shfl_xor(ss, 2);
    float inv = 1.f / fmaxf(sqrtf(ss), 1e-12f);

    uint4 pk4[4];
#pragma unroll
    for (int j = 0; j < 4; ++j) {
      unsigned p[4];
#pragma unroll
      for (int e = 0; e < 4; ++e)
        p[e] = pack2(v[8 * j + 2 * e] * inv, v[8 * j + 2 * e + 1] * inv);
      pk4[j] = *(uint4*)p;
    }

    if (isQ) {
      if (valid) {
        uint4* dst = (uint4*)(qcol + ((size_t)qq * 32 + t) * DD + qt * 32);
#pragma unroll
        for (int j = 0; j < 4; ++j) dst[j] = pk4[j];
      }
    } else {
      uint4* rowp = (uint4*)(ccol + ((size_t)qq * 256 + t) * DD);
#pragma unroll
      for (int j = 0; j < 4; ++j) {
        int kc = qt * 4 + j;
        int p = (kc & 8) | ((kc & 7) ^ (t & 7));
        rowp[p] = pk4[j];
      }
      if (t == 254) {  // duplicate into pad row 255 (row&7 = 7); next row = +16 uint4
        uint4* rowp2 = rowp + 16;
#pragma unroll
        for (int j = 0; j < 4; ++j) {
          int kc = qt * 4 + j;
          int p = (kc & 8) | ((kc & 7) ^ 7);
          rowp2[p] = pk4[j];
        }
      }
    }
  }
}

// ---------------------------------------------------------------------------
// Sim (MFMA): sim[q,c] = (sum_i max_j qcol[q,i]·ccol[c,j]) / denom[q]
// Grid (128, 4), 256 thr = 4 waves, 2 blocks/CU. 4 q per wave (16 q/block),
// 2 c-docs per block processed as 4 half-tiles (128 c-rows = 32 KB each),
// double-buffered: stage(half+1) issued before compute(half) — one barrier
// per half. ccol is pre-swizzled by proj; frag reads use the same XOR.
// ---------------------------------------------------------------------------
__global__ __launch_bounds__(256, 2) void sim_kernel(
    const unsigned short* __restrict__ qcolP,  // [64][32][128], row 31 zero
    const unsigned short* __restrict__ ccol,   // swizzled, row 255 dup
    const int* __restrict__ qmask,
    float* __restrict__ sim) {
  __shared__ unsigned short cbuf[2][128 * 128];  // 2 x 32 KB
  int tid = threadIdx.x, lane = tid & 63, wv = tid >> 6;
  int lm = lane & 15, lq = lane >> 4;
  int qb = blockIdx.y * 16 + wv * 4;  // 4 q per wave
  int c0 = blockIdx.x * 2;

  // B fragments (q side): af[q2][it][kf]
  short8 af[4][2][4];
#pragma unroll
  for (int q2 = 0; q2 < 4; ++q2)
#pragma unroll
    for (int it = 0; it < 2; ++it)
#pragma unroll
      for (int kf = 0; kf < 4; ++kf)
        af[q2][it][kf] = *(const short8*)(qcolP +
            (((size_t)(qb + q2) * 32 + it * 16 + lm) * DD + kf * 32 + lq * 8));

  float dinv[4];
#pragma unroll
  for (int q2 = 0; q2 < 4; ++q2) {
    float v = (lane >= 1 && lane < 32) ? (float)qmask[(qb + q2) * SQ + lane] : 0.f;
    for (int off = 1; off < 64; off <<= 1) v += __shfl_xor(v, off);
    dinv[q2] = 1.f / v;
  }

  const unsigned short* csrc = ccol + (size_t)c0 * SC * DD;  // 4 contiguous halves

  // prologue: stage half 0 into buffer 0
#pragma unroll
  for (int i = 0; i < 8; ++i)
    gl_lds16(csrc + (size_t)(i * 256 + tid) * 8,
             (char*)&cbuf[0][0] + (size_t)(i * 256 + wv * 64) * 16);
  __syncthreads();

  float rmax[4][2];
  for (int ht = 0; ht < 4; ++ht) {  // 2 c-docs x 2 halves
    int b = ht & 1;
    if (!(ht & 1)) {
#pragma unroll
      for (int q2 = 0; q2 < 4; ++q2) {
        rmax[q2][0] = -__builtin_inff();
        rmax[q2][1] = -__builtin_inff();
      }
    }
    if (ht < 3) {  // prefetch next half into other buffer (2-phase)
      const unsigned short* s2 = csrc + (size_t)(ht + 1) * 16384;
#pragma unroll
      for (int i = 0; i < 8; ++i)
        gl_lds16(s2 + (size_t)(i * 256 + tid) * 8,
                 (char*)&cbuf[b ^ 1][0] + (size_t)(i * 256 + wv * 64) * 16);
    }

    for (int jt = 0; jt < 8; ++jt) {
      short8 cf[4];  // A operand: c rows jt*16+lm of this half
#pragma unroll
      for (int kf = 0; kf < 4; ++kf) {
        int row = jt * 16 + lm;
        int kc = kf * 4 + lq;
        int p = (kc & 8) | ((kc & 7) ^ (row & 7));
        cf[kf] = *(const short8*)&cbuf[b][(size_t)(row * 16 + p) * 8];
      }
#pragma unroll
      for (int q2 = 0; q2 < 4; ++q2)
#pragma unroll
        for (int it = 0; it < 2; ++it) {
          f32x4 acc = (f32x4){0.f, 0.f, 0.f, 0.f};
#pragma unroll
          for (int kf = 0; kf < 4; ++kf)
            acc = __builtin_amdgcn_mfma_f32_16x16x32_bf16(cf[kf], af[q2][it][kf], acc, 0, 0, 0);
          float loc = fmaxf(fmaxf(acc[0], acc[1]), fmaxf(acc[2], acc[3]));
          rmax[q2][it] = fmaxf(rmax[q2][it], loc);
        }
    }

    if (ht & 1) {  // finalize doc c = c0 + (ht>>1)
      int c = c0 + (ht >> 1);
#pragma unroll
      for (int q2 = 0; q2 < 4; ++q2) {
        float m0 = rmax[q2][0], m1 = rmax[q2][1];
        m0 = fmaxf(m0, __shfl_xor(m0, 16)); m0 = fmaxf(m0, __shfl_xor(m0, 32));
        m1 = fmaxf(m1, __shfl_xor(m1, 16)); m1 = fmaxf(m1, __shfl_xor(m1, 32));
        // q-row i = lm (+16 for it=1); pad row 31 = (it=1, lm=15) excluded
        float s = m0 + ((lm == 15) ? 0.f : m1);
        s += __shfl_xor(s, 1); s += __shfl_xor(s, 2);
        s += __shfl_xor(s, 4); s += __shfl_xor(s, 8);
        if (lane == 0) sim[(qb + q2) * CN + c] = s * dinv[q2];
      }
    }
    __syncthreads();  // buf[b] consumed by all waves; safe to restage next iter
  }
}

// ---------------------------------------------------------------------------
extern "C" void kernel_launch(void* const* d_in, const int* in_sizes, int n_in,
                              void* d_out, int out_size, void* d_ws, size_t ws_size,
                              hipStream_t stream) {
  const float* q_hidden = (const float*)d_in[0];
  const float* c_hidden = (const float*)d_in[1];
  const float* W = (const float*)d_in[2];
  const float* bias = (const float*)d_in[3];
  const int* q_mask = (const int*)d_in[4];
  const int* c_mask = (const int*)d_in[5];

  float* out = (float*)d_out;
  float* sim = out;                      // 64*256
  float* q_pooled = out + QN * CN;       // 64*768
  float* c_pooled = q_pooled + QN * HD;  // 256*768

  unsigned short* WtS   = (unsigned short*)d_ws;                        // 192 KB
  unsigned short* qcolP = (unsigned short*)((char*)d_ws + (256 << 10)); // 512 KB
  unsigned short* ccol  = (unsigned short*)((char*)d_ws + (1 << 20));   // 16 MB

  prep_kernel<<<DD + QN + CN, 256, 0, stream>>>(W, q_hidden, q_mask, c_hidden, c_mask,
                                                WtS, q_pooled, c_pooled, qcolP);
  proj_kernel<<<526, 256, 0, stream>>>(q_hidden, c_hidden, q_mask, c_mask,
                                       WtS, bias, qcolP, ccol);
  sim_kernel<<<dim3(128, 4), 256, 0, stream>>>(qcolP, ccol, q_mask, sim);
}

// Round 5
// 345.782 us; speedup vs baseline: 1.0974x; 1.0084x over previous
//
#include <hip/hip_runtime.h>
#include <hip/hip_bf16.h>

// Shapes (fixed by the reference)
#define QN 64
#define SQ 32
#define CN 256
#define SC 256
#define HD 768
#define DD 128

typedef __attribute__((ext_vector_type(8))) short short8;   // 8 bf16 = 4 VGPR
typedef __attribute__((ext_vector_type(4))) float f32x4;    // MFMA acc

// ---- bf16 pack helpers (RNE) ----
static __device__ __forceinline__ unsigned short f2bf(float x) {
  unsigned u = __float_as_uint(x);
  unsigned r = 0x7FFFu + ((u >> 16) & 1u);
  return (unsigned short)((u + r) >> 16);
}
static __device__ __forceinline__ unsigned pack2(float a, float b) {
  return (unsigned)f2bf(a) | ((unsigned)f2bf(b) << 16);
}

// ---- async global->LDS, 16B/lane; LDS dest = wave-uniform base + lane*16 ----
typedef const __attribute__((address_space(1))) unsigned int* as1_u32p;
typedef __attribute__((address_space(3))) unsigned int* as3_u32p;
static __device__ __forceinline__ void gl_lds16(const void* g, void* l) {
  __builtin_amdgcn_global_load_lds((as1_u32p)g, (as3_u32p)l, 16, 0, 0);
}

// ---------------------------------------------------------------------------
// Prep (fused):
//  blocks [0,128):  WtS[d][kc'] = bf16(W[k][d]) in 16B chunks (8 bf16), XOR
//                   swizzled within 8-chunk groups: kc' = (kc&~7)|((kc&7)^(d&7)).
//  blocks [128,448): pooled l2norm rows (64 q + 256 c); q rows also zero
//                   qcolP pad row 31.
// ---------------------------------------------------------------------------
__global__ __launch_bounds__(256) void prep_kernel(
    const float* __restrict__ W,
    const float* __restrict__ qh, const int* __restrict__ qm,
    const float* __restrict__ ch, const int* __restrict__ cm,
    unsigned short* __restrict__ WtS,
    float* __restrict__ outq, float* __restrict__ outc,
    unsigned short* __restrict__ qcolP) {
  __shared__ float red[4];
  int bid = blockIdx.x, tid = threadIdx.x;

  if (bid < DD) {  // W transpose-convert, swizzled chunks
    int d = bid;
    if (tid < 96) {
      int kc = tid;
      unsigned p[4];
#pragma unroll
      for (int e = 0; e < 4; ++e) {
        float a = W[(size_t)(kc * 8 + 2 * e) * DD + d];
        float b = W[(size_t)(kc * 8 + 2 * e + 1) * DD + d];
        p[e] = pack2(a, b);
      }
      int kcp = (kc & ~7) | ((kc & 7) ^ (d & 7));
      *(uint4*)&WtS[((size_t)d * 96 + kcp) * 8] = *(uint4*)p;
    }
    return;
  }

  int row = bid - DD;
  const float* src;
  float* dst;
  float m;
  if (row < QN) {
    src = qh + (size_t)row * SQ * HD;
    m = (float)qm[row * SQ];
    dst = outq + (size_t)row * HD;
  } else {
    int b = row - QN;
    src = ch + (size_t)b * SC * HD;
    m = (float)cm[b * SC];
    dst = outc + (size_t)b * HD;
  }
  float ss = 0.f;
  for (int k = tid; k < HD; k += 256) {
    float v = src[k] * m;
    ss += v * v;
  }
  int lane = tid & 63, wv = tid >> 6;
  for (int off = 32; off; off >>= 1) ss += __shfl_xor(ss, off);
  if (lane == 0) red[wv] = ss;
  __syncthreads();
  float tot = red[0] + red[1] + red[2] + red[3];
  float inv = 1.f / fmaxf(sqrtf(tot), 1e-12f);
  for (int k = tid; k < HD; k += 256) dst[k] = src[k] * m * inv;
  if (row < QN && tid < 64)
    ((unsigned*)(qcolP + ((size_t)row * 32 + 31) * DD))[tid] = 0u;
}

// ---------------------------------------------------------------------------
// Projection GEMM (MFMA): col = l2norm(m*(h@W) + b)
//  v5: TLP to hide the per-step barrier drain. Every prior variant kept a
//  __syncthreads per K-step (W dbuf swap), whose implicit s_waitcnt vmcnt(0)
//  drains ALL in-flight loads (A prefetch included) -> pure latency exposure
//  at only 2 blocks/CU. Fix: shrink footprint so FOUR blocks share a CU and
//  their drains overlap other blocks' issue/compute.
//   - M=64/block, 1 row-tile per wave, acc[8] (32 VGPR), Pa/Pb (32 VGPR)
//   - LDS = union(W dbuf 32 KB, cep 33.8 KB) = 33.8 KB -> 4 blocks/CU
//   - __launch_bounds__(256,4) caps VGPR at 128
//   - mask-skip kept: ~50% rows have m=0 -> skip their A loads entirely
//  Blocks [0,1020): c tokens (exact). [1020,1051): q tokens (exact).
// ---------------------------------------------------------------------------
union ProjLDS {
  unsigned short w[2][128 * 64];  // 2 x 16 KB W double-buffer
  float cep[64 * 132];            // 33.8 KB epilogue staging
};

__global__ __launch_bounds__(256, 4) void proj_kernel(
    const float* __restrict__ q_hidden, const float* __restrict__ c_hidden,
    const int* __restrict__ q_mask, const int* __restrict__ c_mask,
    const unsigned short* __restrict__ WtS, const float* __restrict__ bias,
    unsigned short* __restrict__ qcol, unsigned short* __restrict__ ccol) {
  __shared__ ProjLDS u;
  int bx = blockIdx.x;
  int isQ = (bx >= 1020) ? 1 : 0;
  int base = isQ ? (bx - 1020) : bx;
  int tid = threadIdx.x, lane = tid & 63, wv = tid >> 6;
  int lm = lane & 15, lq = lane >> 4;

  // ---- this lane's A row (wave wv owns rows wv*16..wv*16+15) + mask ----
  int g = base * 64 + wv * 16 + lm;
  const float* abase;
  int pm;
  if (isQ) {  // 31 blocks * 64 = 1984 = 64*31 exact
    int qq = g / 31, t = g - qq * 31;
    abase = q_hidden + ((size_t)qq * SQ + t + 1) * HD + lq * 8;
    pm = q_mask[qq * SQ + t + 1];
  } else {    // 1020 blocks * 64 = 65280 = 256*255 exact
    int cb = g / 255, t = g - cb * 255;
    abase = c_hidden + ((size_t)cb * SC + t + 1) * HD + lq * 8;
    pm = c_mask[cb * SC + t + 1];
  }

  // ---- W staging sources: 4 slots/thread (linear copy of pre-swizzled WtS) ----
  const unsigned short* wptr[4];
#pragma unroll
  for (int i = 0; i < 4; ++i) {
    int d = i * 32 + (tid >> 3);
    wptr[i] = WtS + ((size_t)d * 96 + (tid & 7)) * 8;
  }

  f32x4 acc[8];
#pragma unroll
  for (int n = 0; n < 8; ++n) acc[n] = (f32x4){0.f, 0.f, 0.f, 0.f};

  // A prefetch double-set; zero-init so masked (never-loaded) rows are exact 0.
  float4 Pa[4], Pb[4];
#pragma unroll
  for (int i = 0; i < 4; ++i) {
    Pa[i] = (float4){0.f, 0.f, 0.f, 0.f};
    Pb[i] = (float4){0.f, 0.f, 0.f, 0.f};
  }

  // ---- prologue: A(0)->Pa (masked lanes skip), W(0)->buf0 (DMA) ----
  if (pm) {
    Pa[0] = *(const float4*)(abase);
    Pa[1] = *(const float4*)(abase + 4);
    Pa[2] = *(const float4*)(abase + 32);
    Pa[3] = *(const float4*)(abase + 36);
  }
#pragma unroll
  for (int i = 0; i < 4; ++i)
    gl_lds16(wptr[i], (char*)&u.w[0][0] + (size_t)(i * 256 + wv * 64) * 16);
  __syncthreads();

  // One pipeline step: compute step t from (PC, buf CB); prefetch t+1 into
  // (PN, buf NB) first. The end-of-step barrier drains everything anyway;
  // the hiding comes from the 3 OTHER blocks on this CU.
#define PROJ_STEP(t, PC, PN, CB, NB, PREFETCH)                                 \
  {                                                                            \
    if (PREFETCH) {                                                            \
      if (pm) {                                                                \
        PN[0] = *(const float4*)(abase + (t + 1) * 64);                        \
        PN[1] = *(const float4*)(abase + (t + 1) * 64 + 4);                    \
        PN[2] = *(const float4*)(abase + (t + 1) * 64 + 32);                   \
        PN[3] = *(const float4*)(abase + (t + 1) * 64 + 36);                   \
      }                                                                        \
      _Pragma("unroll")                                                        \
      for (int i = 0; i < 4; ++i)                                              \
        gl_lds16(wptr[i] + (t + 1) * 64,                                       \
                 (char*)&u.w[NB][0] + (size_t)(i * 256 + wv * 64) * 16);       \
    }                                                                          \
    _Pragma("unroll")                                                          \
    for (int w = 0; w < 2; ++w) {                                              \
      float4 a0 = PC[w * 2], a1 = PC[w * 2 + 1];                               \
      unsigned pk[4];                                                          \
      pk[0] = pack2(a0.x, a0.y); pk[1] = pack2(a0.z, a0.w);                    \
      pk[2] = pack2(a1.x, a1.y); pk[3] = pack2(a1.z, a1.w);                    \
      short8 afr = *(short8*)pk;                                               \
      _Pragma("unroll")                                                        \
      for (int nt = 0; nt < 8; ++nt) {                                         \
        int d = nt * 16 + lm;                                                  \
        int pc = (w * 4 + lq) ^ (lm & 7);                                      \
        short8 bfr = *(const short8*)&u.w[CB][d * 64 + pc * 8];                \
        acc[nt] = __builtin_amdgcn_mfma_f32_16x16x32_bf16(afr, bfr,            \
                                                          acc[nt], 0, 0, 0);  \
      }                                                                        \
    }                                                                          \
    __syncthreads();                                                           \
  }

#pragma unroll
  for (int s = 0; s < 12; s += 2) {
    PROJ_STEP(s, Pa, Pb, 0, 1, 1);
    PROJ_STEP(s + 1, Pb, Pa, 1, 0, (s + 1 < 11));
  }
#undef PROJ_STEP

  // ---- epilogue: 64 rows through cep (all W LDS reads done at last barrier) ----
#pragma unroll
  for (int nt = 0; nt < 8; ++nt)
#pragma unroll
    for (int r = 0; r < 4; ++r) {
      int row = wv * 16 + lq * 4 + r;
      u.cep[row * 132 + nt * 16 + lm] = acc[nt][r];
    }
  __syncthreads();

  int tk = tid >> 2, qt = tid & 3;  // row 0..63, 32-d quarter
  int g2 = base * 64 + tk;
  int qq, t;
  float fm;
  if (isQ) {
    qq = g2 / 31; t = g2 - qq * 31;
    fm = (float)q_mask[qq * SQ + t + 1];
  } else {
    qq = g2 / 255; t = g2 - qq * 255;
    fm = (float)c_mask[qq * SC + t + 1];
  }

  float v[32];
  float ss = 0.f;
#pragma unroll
  for (int j = 0; j < 8; ++j) {
    float4 cv = *(const float4*)&u.cep[tk * 132 + qt * 32 + j * 4];
    float4 bv = *(const float4*)&bias[qt * 32 + j * 4];
    v[4 * j + 0] = cv.x * fm + bv.x; v[4 * j + 1] = cv.y * fm + bv.y;
    v[4 * j + 2] = cv.z * fm + bv.z; v[4 * j + 3] = cv.w * fm + bv.w;
#pragma unroll
    for (int e = 0; e < 4; ++e) ss += v[4 * j + e] * v[4 * j + e];
  }
  ss += __shfl_xor(ss, 1);
  ss += __shfl_xor(ss, 2);
  float inv = 1.f / fmaxf(sqrtf(ss), 1e-12f);

  uint4 pk4[4];
#pragma unroll
  for (int j = 0; j < 4; ++j) {
    unsigned p[4];
#pragma unroll
    for (int e = 0; e < 4; ++e)
      p[e] = pack2(v[8 * j + 2 * e] * inv, v[8 * j + 2 * e + 1] * inv);
    pk4[j] = *(uint4*)p;
  }

  if (isQ) {
    uint4* dst = (uint4*)(qcol + ((size_t)qq * 32 + t) * DD + qt * 32);
#pragma unroll
    for (int j = 0; j < 4; ++j) dst[j] = pk4[j];
  } else {
    uint4* rowp = (uint4*)(ccol + ((size_t)qq * 256 + t) * DD);
#pragma unroll
    for (int j = 0; j < 4; ++j) {
      int kc = qt * 4 + j;
      int p = (kc & 8) | ((kc & 7) ^ (t & 7));
      rowp[p] = pk4[j];
    }
    if (t == 254) {  // duplicate into pad row 255 (row&7 = 7); next row = +16 uint4
      uint4* rowp2 = rowp + 16;
#pragma unroll
      for (int j = 0; j < 4; ++j) {
        int kc = qt * 4 + j;
        int p = (kc & 8) | ((kc & 7) ^ 7);
        rowp2[p] = pk4[j];
      }
    }
  }
}

// ---------------------------------------------------------------------------
// Sim (MFMA): sim[q,c] = (sum_i max_j qcol[q,i]·ccol[c,j]) / denom[q]
// Grid (128, 4), 256 thr = 4 waves, 2 blocks/CU. 4 q per wave (16 q/block),
// 2 c-docs per block processed as 4 half-tiles (128 c-rows = 32 KB each),
// double-buffered: stage(half+1) issued before compute(half) — one barrier
// per half. ccol is pre-swizzled by proj; frag reads use the same XOR.
// ---------------------------------------------------------------------------
__global__ __launch_bounds__(256, 2) void sim_kernel(
    const unsigned short* __restrict__ qcolP,  // [64][32][128], row 31 zero
    const unsigned short* __restrict__ ccol,   // swizzled, row 255 dup
    const int* __restrict__ qmask,
    float* __restrict__ sim) {
  __shared__ unsigned short cbuf[2][128 * 128];  // 2 x 32 KB
  int tid = threadIdx.x, lane = tid & 63, wv = tid >> 6;
  int lm = lane & 15, lq = lane >> 4;
  int qb = blockIdx.y * 16 + wv * 4;  // 4 q per wave
  int c0 = blockIdx.x * 2;

  // B fragments (q side): af[q2][it][kf]
  short8 af[4][2][4];
#pragma unroll
  for (int q2 = 0; q2 < 4; ++q2)
#pragma unroll
    for (int it = 0; it < 2; ++it)
#pragma unroll
      for (int kf = 0; kf < 4; ++kf)
        af[q2][it][kf] = *(const short8*)(qcolP +
            (((size_t)(qb + q2) * 32 + it * 16 + lm) * DD + kf * 32 + lq * 8));

  float dinv[4];
#pragma unroll
  for (int q2 = 0; q2 < 4; ++q2) {
    float v = (lane >= 1 && lane < 32) ? (float)qmask[(qb + q2) * SQ + lane] : 0.f;
    for (int off = 1; off < 64; off <<= 1) v += __shfl_xor(v, off);
    dinv[q2] = 1.f / v;
  }

  const unsigned short* csrc = ccol + (size_t)c0 * SC * DD;  // 4 contiguous halves

  // prologue: stage half 0 into buffer 0
#pragma unroll
  for (int i = 0; i < 8; ++i)
    gl_lds16(csrc + (size_t)(i * 256 + tid) * 8,
             (char*)&cbuf[0][0] + (size_t)(i * 256 + wv * 64) * 16);
  __syncthreads();

  float rmax[4][2];
  for (int ht = 0; ht < 4; ++ht) {  // 2 c-docs x 2 halves
    int b = ht & 1;
    if (!(ht & 1)) {
#pragma unroll
      for (int q2 = 0; q2 < 4; ++q2) {
        rmax[q2][0] = -__builtin_inff();
        rmax[q2][1] = -__builtin_inff();
      }
    }
    if (ht < 3) {  // prefetch next half into other buffer (2-phase)
      const unsigned short* s2 = csrc + (size_t)(ht + 1) * 16384;
#pragma unroll
      for (int i = 0; i < 8; ++i)
        gl_lds16(s2 + (size_t)(i * 256 + tid) * 8,
                 (char*)&cbuf[b ^ 1][0] + (size_t)(i * 256 + wv * 64) * 16);
    }

    for (int jt = 0; jt < 8; ++jt) {
      short8 cf[4];  // A operand: c rows jt*16+lm of this half
#pragma unroll
      for (int kf = 0; kf < 4; ++kf) {
        int row = jt * 16 + lm;
        int kc = kf * 4 + lq;
        int p = (kc & 8) | ((kc & 7) ^ (row & 7));
        cf[kf] = *(const short8*)&cbuf[b][(size_t)(row * 16 + p) * 8];
      }
#pragma unroll
      for (int q2 = 0; q2 < 4; ++q2)
#pragma unroll
        for (int it = 0; it < 2; ++it) {
          f32x4 acc = (f32x4){0.f, 0.f, 0.f, 0.f};
#pragma unroll
          for (int kf = 0; kf < 4; ++kf)
            acc = __builtin_amdgcn_mfma_f32_16x16x32_bf16(cf[kf], af[q2][it][kf], acc, 0, 0, 0);
          float loc = fmaxf(fmaxf(acc[0], acc[1]), fmaxf(acc[2], acc[3]));
          rmax[q2][it] = fmaxf(rmax[q2][it], loc);
        }
    }

    if (ht & 1) {  // finalize doc c = c0 + (ht>>1)
      int c = c0 + (ht >> 1);
#pragma unroll
      for (int q2 = 0; q2 < 4; ++q2) {
        float m0 = rmax[q2][0], m1 = rmax[q2][1];
        m0 = fmaxf(m0, __shfl_xor(m0, 16)); m0 = fmaxf(m0, __shfl_xor(m0, 32));
        m1 = fmaxf(m1, __shfl_xor(m1, 16)); m1 = fmaxf(m1, __shfl_xor(m1, 32));
        // q-row i = lm (+16 for it=1); pad row 31 = (it=1, lm=15) excluded
        float s = m0 + ((lm == 15) ? 0.f : m1);
        s += __shfl_xor(s, 1); s += __shfl_xor(s, 2);
        s += __shfl_xor(s, 4); s += __shfl_xor(s, 8);
        if (lane == 0) sim[(qb + q2) * CN + c] = s * dinv[q2];
      }
    }
    __syncthreads();  // buf[b] consumed by all waves; safe to restage next iter
  }
}

// ---------------------------------------------------------------------------
extern "C" void kernel_launch(void* const* d_in, const int* in_sizes, int n_in,
                              void* d_out, int out_size, void* d_ws, size_t ws_size,
                              hipStream_t stream) {
  const float* q_hidden = (const float*)d_in[0];
  const float* c_hidden = (const float*)d_in[1];
  const float* W = (const float*)d_in[2];
  const float* bias = (const float*)d_in[3];
  const int* q_mask = (const int*)d_in[4];
  const int* c_mask = (const int*)d_in[5];

  float* out = (float*)d_out;
  float* sim = out;                      // 64*256
  float* q_pooled = out + QN * CN;       // 64*768
  float* c_pooled = q_pooled + QN * HD;  // 256*768

  unsigned short* WtS   = (unsigned short*)d_ws;                        // 192 KB
  unsigned short* qcolP = (unsigned short*)((char*)d_ws + (256 << 10)); // 512 KB
  unsigned short* ccol  = (unsigned short*)((char*)d_ws + (1 << 20));   // 16 MB

  prep_kernel<<<DD + QN + CN, 256, 0, stream>>>(W, q_hidden, q_mask, c_hidden, c_mask,
                                                WtS, q_pooled, c_pooled, qcolP);
  proj_kernel<<<1051, 256, 0, stream>>>(q_hidden, c_hidden, q_mask, c_mask,
                                        WtS, bias, qcolP, ccol);
  sim_kernel<<<dim3(128, 4), 256, 0, stream>>>(qcolP, ccol, q_mask, sim);
}